// Round 3
// baseline (369.249 us; speedup 1.0000x reference)
//
#include <hip/hip_runtime.h>

#define NV 8192
#define NH 4096
#define TPB 256
#define ROW4 (NV / 4)              // 2048 float4 per row
#define VBLK (ROW4 / TPB)          // 8 blocks in x

typedef float f32x4 __attribute__((ext_vector_type(4)));

// output layout (flat float offsets, reference return order)
#define OFF_B   ((size_t)0)
#define OFF_WT  ((size_t)NV)
#define OFF_SIG ((size_t)NV + (size_t)NH * (size_t)NV)
#define OFF_MUH (OFF_SIG + 1)
#define OFF_VHD (OFF_MUH + NH)

// ws layout: [C * NV] floats bTE partials (as float4 blocks), then [C * VBLK] trace partials
// where C = NH / HPB = number of h-chunks.

template <int HPB>
__global__ __launch_bounds__(TPB) void main_t(
    const float4* __restrict__ varvhTE4,
    const float4* __restrict__ varvh4,
    const float* __restrict__ varh_diagTE,
    const float* __restrict__ varh_diag,
    const float* __restrict__ muh,
    const float* __restrict__ muhTE,
    float* __restrict__ out,
    float* __restrict__ ws)
{
    __shared__ float4 coef_s[HPB];
    const int t  = threadIdx.x;
    const int ch = blockIdx.y;              // h-chunk index
    const int h0 = ch * HPB;
    const int C  = NH / HPB;

    // per-h coefficients: {inv, inv*muh, d*muh - inv*muhTE, d}
    if (t < HPB) {
        int h = h0 + t;
        float inv = 1.0f / varh_diag[h];
        float d   = inv * varh_diagTE[h] * inv;
        float m   = muh[h];
        coef_s[t] = make_float4(inv, inv * m, d * m - inv * muhTE[h], d);
    }
    __syncthreads();

    const int v4 = blockIdx.x * TPB + t;    // float4 column index
    f32x4* wt4 = (f32x4*)(out + OFF_WT);

    float bx = 0.f, by = 0.f, bz = 0.f, bw = 0.f;
    float tr = 0.f;

    #pragma unroll 8
    for (int hh = 0; hh < HPB; ++hh) {
        float4 c = coef_s[hh];
        size_t idx = (size_t)(h0 + hh) * ROW4 + (size_t)v4;
        float4 aTE = varvhTE4[idx];
        float4 a   = varvh4[idx];

        f32x4 w;
        w.x = c.x * aTE.x - c.w * a.x;
        w.y = c.x * aTE.y - c.w * a.y;
        w.z = c.x * aTE.z - c.w * a.z;
        w.w = c.x * aTE.w - c.w * a.w;
        __builtin_nontemporal_store(w, &wt4[idx]);

        bx += c.z * a.x - c.y * aTE.x;
        by += c.z * a.y - c.y * aTE.y;
        bz += c.z * a.z - c.y * aTE.z;
        bw += c.z * a.w - c.y * aTE.w;

        float dot = aTE.x * a.x + aTE.y * a.y + aTE.z * a.z + aTE.w * a.w;
        float sq  = a.x * a.x + a.y * a.y + a.z * a.z + a.w * a.w;
        tr += 2.0f * c.x * dot - c.w * sq;
    }

    // bTE partial: one vectorized store per thread, no atomics
    f32x4* pb4 = (f32x4*)ws;                // [C][ROW4] float4
    f32x4 p; p.x = bx; p.y = by; p.z = bz; p.w = bw;
    pb4[(size_t)ch * ROW4 + v4] = p;

    // block-reduce trace partial: wave64 shuffle, then LDS across 4 waves
    for (int off = 32; off > 0; off >>= 1)
        tr += __shfl_down(tr, off);
    __shared__ float wsum[TPB / 64];
    if ((t & 63) == 0) wsum[t >> 6] = tr;
    __syncthreads();
    if (t == 0)
        ws[(size_t)C * NV + (size_t)ch * VBLK + blockIdx.x] =
            wsum[0] + wsum[1] + wsum[2] + wsum[3];
}

// reduce bTE partials + add muvTE; also copy muhTE / varh_diagTE passthroughs
__global__ __launch_bounds__(TPB) void red_k(
    const float* __restrict__ ws,
    const float4* __restrict__ muv4,
    const float* __restrict__ varh_diagTE,
    const float* __restrict__ muhTE,
    int C,
    float* __restrict__ out)
{
    const int t  = threadIdx.x;
    const int v4 = blockIdx.x * TPB + t;    // grid = VBLK blocks covers ROW4
    const f32x4* pb4 = (const f32x4*)ws;

    float4 m = muv4[v4];
    float sx = m.x, sy = m.y, sz = m.z, sw = m.w;
    #pragma unroll 4
    for (int c = 0; c < C; ++c) {
        f32x4 p = pb4[(size_t)c * ROW4 + v4];
        sx += p.x; sy += p.y; sz += p.z; sw += p.w;
    }
    f32x4* ob4 = (f32x4*)(out + OFF_B);
    f32x4 r; r.x = sx; r.y = sy; r.z = sz; r.w = sw;
    ob4[v4] = r;

    // passthrough copies (NH = 4096, grid threads = VBLK*TPB = 2048)
    int gthreads = VBLK * TPB;
    for (int i = blockIdx.x * TPB + t; i < NH; i += gthreads) {
        out[OFF_MUH + i] = muhTE[i];
        out[OFF_VHD + i] = varh_diagTE[i];
    }
}

__global__ __launch_bounds__(TPB) void fin_k(
    const float* __restrict__ ws,
    const float* __restrict__ varvbarTE,
    int C,
    float* __restrict__ out)
{
    const float* tr_partial = ws + (size_t)C * NV;
    const int npart = C * VBLK;
    int t = threadIdx.x;
    float s = 0.f;
    for (int i = t; i < npart; i += TPB) s += tr_partial[i];
    for (int off = 32; off > 0; off >>= 1)
        s += __shfl_down(s, off);
    __shared__ float wsum[TPB / 64];
    if ((t & 63) == 0) wsum[t >> 6] = s;
    __syncthreads();
    if (t == 0) {
        float tr = wsum[0] + wsum[1] + wsum[2] + wsum[3];
        out[OFF_SIG] = (varvbarTE[0] - tr) / (float)NV;
    }
}

static inline size_t ws_need(int C) {
    return ((size_t)C * NV + (size_t)C * VBLK) * sizeof(float);
}

extern "C" void kernel_launch(void* const* d_in, const int* in_sizes, int n_in,
                              void* d_out, int out_size, void* d_ws, size_t ws_size,
                              hipStream_t stream) {
    const float* muvTE       = (const float*)d_in[0];
    const float* varvhTE     = (const float*)d_in[1];
    const float* varh_diagTE = (const float*)d_in[2];
    const float* varh_diag   = (const float*)d_in[3];
    const float* muh         = (const float*)d_in[4];
    const float* varvh       = (const float*)d_in[5];
    const float* muhTE       = (const float*)d_in[6];
    const float* varvbarTE   = (const float*)d_in[7];
    float* out = (float*)d_out;
    float* ws  = (float*)d_ws;

    const float4* A = (const float4*)varvhTE;
    const float4* B = (const float4*)varvh;

    int C;  // number of h-chunks, sized to available workspace
    if (ws_size >= ws_need(256)) {
        C = 256;
        main_t<16><<<dim3(VBLK, C), TPB, 0, stream>>>(
            A, B, varh_diagTE, varh_diag, muh, muhTE, out, ws);
    } else if (ws_size >= ws_need(128)) {
        C = 128;
        main_t<32><<<dim3(VBLK, C), TPB, 0, stream>>>(
            A, B, varh_diagTE, varh_diag, muh, muhTE, out, ws);
    } else if (ws_size >= ws_need(64)) {
        C = 64;
        main_t<64><<<dim3(VBLK, C), TPB, 0, stream>>>(
            A, B, varh_diagTE, varh_diag, muh, muhTE, out, ws);
    } else {
        C = 32;
        main_t<128><<<dim3(VBLK, C), TPB, 0, stream>>>(
            A, B, varh_diagTE, varh_diag, muh, muhTE, out, ws);
    }

    red_k<<<VBLK, TPB, 0, stream>>>((const float*)ws, (const float4*)muvTE,
                                    varh_diagTE, muhTE, C, out);
    fin_k<<<1, TPB, 0, stream>>>((const float*)ws, varvbarTE, C, out);
}